// Round 10
// baseline (259.561 us; speedup 1.0000x reference)
//
#include <hip/hip_runtime.h>

// CrossCueFusion on MI355X (gfx950) — round 10 (DIAGNOSTIC: t_attention).
// r9 XCD-band swizzle regressed (219.4 vs 214.6) -> reverted; L2-banding theory
// dead (L3 already absorbs the small intermediates' re-reads).
// Ledger: kernels total 95us (r8), harness ~120us fixed, pipe floors ~60us.
// Need the per-kernel split before spending another optimization: k_attention
// is idempotent -> launch 3x. dur = 214.6 + 2*t_attn (exact, single unknown).

using bf16x8 = __attribute__((ext_vector_type(8))) short;
using f32x4  = __attribute__((ext_vector_type(4))) float;
using f32x16 = __attribute__((ext_vector_type(16))) float;
typedef unsigned short u16;
typedef unsigned int   u32;

__device__ __forceinline__ u16 f2bf(float f) {  // RNE fp32 -> bf16
  u32 u = __builtin_bit_cast(u32, f);
  u = (u + 0x7fffu + ((u >> 16) & 1u)) >> 16;
  return (u16)u;
}
__device__ __forceinline__ float bf2f(u16 v) {
  u32 u = ((u32)v) << 16;
  return __builtin_bit_cast(float, u);
}
__device__ __forceinline__ float bfLO(u32 u) { return __builtin_bit_cast(float, u << 16); }
__device__ __forceinline__ float bfHI(u32 u) { return __builtin_bit_cast(float, u & 0xffff0000u); }
// pack two fp32 -> (bf16 hi|lo) by truncation: one v_perm_b32
__device__ __forceinline__ u32 pktr(float lo, float hi) {
  return __builtin_amdgcn_perm(__builtin_bit_cast(u32, hi),
                               __builtin_bit_cast(u32, lo), 0x07060302u);
}
__device__ __forceinline__ f32x4 mfma16(bf16x8 a, bf16x8 b, f32x4 c) {
  return __builtin_amdgcn_mfma_f32_16x16x32_bf16(a, b, c, 0, 0, 0);
}
__device__ __forceinline__ f32x16 mfma32(bf16x8 a, bf16x8 b, f32x16 c) {
  return __builtin_amdgcn_mfma_f32_32x32x16_bf16(a, b, c, 0, 0, 0);
}
__device__ __forceinline__ f32x16 zero16() {
  f32x16 z = {0,0,0,0,0,0,0,0,0,0,0,0,0,0,0,0};
  return z;
}
__device__ __forceinline__ void store4bf(u16* dst, f32x4 v) {
  u32 lo = (u32)f2bf(v[0]) | ((u32)f2bf(v[1]) << 16);
  u32 hi = (u32)f2bf(v[2]) | ((u32)f2bf(v[3]) << 16);
  *(uint2*)dst = make_uint2(lo, hi);
}
__device__ __forceinline__ float sum16(const float* e) {  // pairwise tree, depth 4
  float s0 = e[0] + e[1], s1 = e[2] + e[3], s2 = e[4] + e[5], s3 = e[6] + e[7];
  float s4 = e[8] + e[9], s5 = e[10] + e[11], s6 = e[12] + e[13], s7 = e[14] + e[15];
  float a = s0 + s1, b = s2 + s3, c = s4 + s5, d = s6 + s7;
  return (a + b) + (c + d);
}

struct WPtrs { const float* p[13]; };

// ================= T1: weight prep + border zero + transpose (fused) ============
// grid: [0,13) prep | [13,138) zero-borders | [138,4234) transpose
__global__ void k_pre(WPtrs wp, u16* __restrict__ wConv, u16* __restrict__ w1x1,
                      const float* __restrict__ mono, const float* __restrict__ cv,
                      u16* __restrict__ monoT, u16* __restrict__ cvT,
                      u16* __restrict__ m1T, u16* __restrict__ x1T, u16* __restrict__ r1T) {
  int bx = blockIdx.x, t = threadIdx.x;
  if (bx < 13) {
    if (bx < 6) {
      const float* s = wp.p[bx];
      u16* d = wConv + bx * 9216;  // [tap][co][ci]
      for (int i = t; i < 9216; i += 256) {
        int tap = i >> 10, co = (i >> 5) & 31, ci = i & 31;
        d[i] = f2bf(s[co * 288 + ci * 9 + tap]);
      }
    } else {
      const float* s = wp.p[bx];
      u16* d = w1x1 + (bx - 6) * 1024;
      for (int i = t; i < 1024; i += 256) d[i] = f2bf(s[i]);
    }
    return;
  }
  if (bx < 138) {
    int zb = bx - 13;
    int buf = zb % 5, blk = zb / 5;
    u16* b; int Hp, Wp;
    switch (buf) {
      case 0: b = monoT; Hp = 258; Wp = 514; break;
      case 1: b = cvT;   Hp = 258; Wp = 514; break;
      case 2: b = m1T;   Hp = 130; Wp = 258; break;
      case 3: b = x1T;   Hp = 130; Wp = 258; break;
      default: b = r1T;  Hp = 258; Wp = 514; break;
    }
    int id = blk * 256 + t;
    int cell = id >> 2, c8 = (id & 3) << 3;
    if (cell >= 2 * (Hp + Wp)) return;
    int r, c;
    if (cell < Wp)              { r = 0;                 c = cell; }
    else if (cell < 2 * Wp)     { r = Hp - 1;            c = cell - Wp; }
    else if (cell < 2 * Wp + Hp){ r = cell - 2 * Wp;     c = 0; }
    else                        { r = cell - 2 * Wp - Hp; c = Wp - 1; }
    bf16x8 z = {0, 0, 0, 0, 0, 0, 0, 0};
    *(bf16x8*)&b[(r * Wp + c) * 32 + c8] = z;
    return;
  }
  // transpose NCHW fp32 -> padded HWC bf16
  int idx = bx - 138;
  int xb = idx & 7, y = (idx >> 3) & 255, z = idx >> 11;
  const float* src = z ? cv : mono;
  u16* dst = z ? cvT : monoT;
  int x0 = xb << 6;
  __shared__ u16 tile[64][40];
  int ci = t >> 3, kx = (t & 7) << 3;
  const float* sp = src + ci * 131072 + y * 512 + x0 + kx;
  float4 a = *(const float4*)sp;
  float4 bb = *(const float4*)(sp + 4);
  tile[kx + 0][ci] = f2bf(a.x); tile[kx + 1][ci] = f2bf(a.y);
  tile[kx + 2][ci] = f2bf(a.z); tile[kx + 3][ci] = f2bf(a.w);
  tile[kx + 4][ci] = f2bf(bb.x); tile[kx + 5][ci] = f2bf(bb.y);
  tile[kx + 6][ci] = f2bf(bb.z); tile[kx + 7][ci] = f2bf(bb.w);
  __syncthreads();
  int x = t >> 2, c8 = (t & 3) << 3;
  bf16x8 v = *(bf16x8*)&tile[x][c8];
  *(bf16x8*)(dst + ((y + 1) * 514 + (x0 + x + 1)) * 32 + c8) = v;
}

// ================= shared 3x3 conv body (16 px x 32 co per wave) ================
__device__ __forceinline__ void conv3x3_body(int bxl, int tid,
    const u16* __restrict__ inT, int Wp, const u16* __restrict__ w9,
    const float* __restrict__ bias, u16* __restrict__ out, int outPitch,
    int outOff, int Ho, int tprShift, int stride) {
  int wid = (bxl * 256 + tid) >> 6;
  int lane = tid & 63, ln = lane & 15, q = lane >> 4;
  int y = wid >> tprShift;
  int x0 = (wid & ((1 << tprShift) - 1)) << 4;
  if (y >= Ho) return;
  f32x4 acc0 = *(const f32x4*)(bias + q * 4);
  f32x4 acc1 = *(const f32x4*)(bias + 16 + q * 4);
  const u16* ib = inT + (stride * y * Wp + stride * (x0 + ln)) * 32 + q * 8;
  const u16* wb = w9 + ln * 32 + q * 8;
#pragma unroll
  for (int dy = 0; dy < 3; ++dy)
#pragma unroll
    for (int dx = 0; dx < 3; ++dx) {
      int tap = dy * 3 + dx;
      bf16x8 bf = *(const bf16x8*)(ib + (dy * Wp + dx) * 32);
      acc0 = mfma16(*(const bf16x8*)(wb + tap * 1024), bf, acc0);
      acc1 = mfma16(*(const bf16x8*)(wb + tap * 1024 + 512), bf, acc1);
    }
#pragma unroll
  for (int r = 0; r < 4; ++r) { acc0[r] = fmaxf(acc0[r], 0.f); acc1[r] = fmaxf(acc1[r], 0.f); }
  u16* ob = out + (outOff + y * outPitch + x0 + ln) * 32;
  store4bf(ob + q * 4, acc0);
  store4bf(ob + 16 + q * 4, acc1);
}

// ================= T2: the three big convs (fused) ==============================
// [0,512) mono stride-2 | [512,1024) cv stride-2 | [1024,3072) mono residual s1
__global__ void k_convs(const u16* __restrict__ monoT, const u16* __restrict__ cvT,
                        const u16* __restrict__ wConv,
                        const float* me_b1, const float* xe_b1, const float* mr_b1,
                        u16* __restrict__ m1T, u16* __restrict__ x1T, u16* __restrict__ r1T) {
  int bx = blockIdx.x;
  if (bx < 512)
    conv3x3_body(bx, threadIdx.x, monoT, 514, wConv + 0 * 9216, me_b1, m1T, 258, 259, 128, 4, 2);
  else if (bx < 1024)
    conv3x3_body(bx - 512, threadIdx.x, cvT, 514, wConv + 2 * 9216, xe_b1, x1T, 258, 259, 128, 4, 2);
  else
    conv3x3_body(bx - 1024, threadIdx.x, monoT, 514, wConv + 4 * 9216, mr_b1, r1T, 514, 515, 256, 5, 1);
}

// ================= T3+T4 merged: feature conv + q/k/v projections ===============
// grid (128, 2): y=0 mono branch (which 0..2), y=1 multi branch (which 3..5).
__global__ void k_featproj(const u16* __restrict__ m1T, const u16* __restrict__ x1T,
                           const u16* __restrict__ wConv, const u16* __restrict__ w1x1,
                           const float* me_b2, const float* xe_b2,
                           const float* mq_b, const float* mk_b, const float* mv_b,
                           const float* xq_b, const float* xk_b, const float* xv_b,
                           u16* Qm, u16* Km, u16* Vm, u16* Qx, u16* Kx, u16* Vx) {
  int bx = blockIdx.x, br = blockIdx.y;
  const u16* inT = br ? x1T : m1T;
  const u16* w9 = wConv + (br ? 3 : 1) * 9216;
  const float* bias2 = br ? xe_b2 : me_b2;
  __shared__ u16 fs[64][40];
  int tid = threadIdx.x, wave = tid >> 6, lane = tid & 63, ln = lane & 15, q = lane >> 4;
  int fy = bx >> 1, x0 = (bx & 1) * 64 + wave * 16;  // feat image [64][128]
  {
    f32x4 acc0 = *(const f32x4*)(bias2 + q * 4);
    f32x4 acc1 = *(const f32x4*)(bias2 + 16 + q * 4);
    const u16* ib = inT + (2 * fy * 258 + 2 * (x0 + ln)) * 32 + q * 8;
    const u16* wb = w9 + ln * 32 + q * 8;
#pragma unroll
    for (int dy = 0; dy < 3; ++dy)
#pragma unroll
      for (int dx = 0; dx < 3; ++dx) {
        int tap = dy * 3 + dx;
        bf16x8 bf = *(const bf16x8*)(ib + (dy * 258 + dx) * 32);
        acc0 = mfma16(*(const bf16x8*)(wb + tap * 1024), bf, acc0);
        acc1 = mfma16(*(const bf16x8*)(wb + tap * 1024 + 512), bf, acc1);
      }
#pragma unroll
    for (int r = 0; r < 4; ++r) { acc0[r] = fmaxf(acc0[r], 0.f); acc1[r] = fmaxf(acc1[r], 0.f); }
    int row = wave * 16 + ln;
    store4bf(&fs[row][q * 4], acc0);
    store4bf(&fs[row][16 + q * 4], acc1);
  }
  __syncthreads();
  int p = fy * 128 + x0 + ln;                       // global pixel [0,8192)
  bf16x8 bf = *(const bf16x8*)&fs[wave * 16 + ln][q * 8];
#pragma unroll
  for (int wh = 0; wh < 3; ++wh) {
    int which = br * 3 + wh;
    const float* bias; u16* dst; float scale = 1.f; int cmode = 0;
    switch (which) {
      case 0: bias = mq_b; dst = Qm; scale = 1.4426950408889634f; break;
      case 1: bias = mk_b; dst = Km; break;
      case 2: bias = mv_b; dst = Vm; cmode = 1; break;
      case 3: bias = xq_b; dst = Qx; scale = 1.4426950408889634f; break;
      case 4: bias = xk_b; dst = Kx; break;
      default: bias = xv_b; dst = Vx; cmode = 1; break;
    }
    const u16* w = w1x1 + which * 1024;
    bf16x8 a0 = *(const bf16x8*)(w + ln * 32 + q * 8);
    bf16x8 a1 = *(const bf16x8*)(w + (16 + ln) * 32 + q * 8);
    f32x4 acc0 = *(const f32x4*)(bias + q * 4);
    f32x4 acc1 = *(const f32x4*)(bias + 16 + q * 4);
    acc0 = mfma16(a0, bf, acc0);
    acc1 = mfma16(a1, bf, acc1);
#pragma unroll
    for (int r = 0; r < 4; ++r) { acc0[r] *= scale; acc1[r] *= scale; }
    if (!cmode) {  // i-major [8192][32]
      store4bf(dst + p * 32 + q * 4, acc0);
      store4bf(dst + p * 32 + 16 + q * 4, acc1);
    } else {       // c-major, pi-permuted within each 64-column block
      int jl = p & 63, jb = p & ~63;
      int pj = jb + (jl >> 5) * 32 + ((jl >> 4) & 1) * 16 + ((jl >> 2) & 1) * 8
             + ((jl >> 3) & 1) * 4 + (jl & 3);
#pragma unroll
      for (int r = 0; r < 4; ++r) {
        dst[(q * 4 + r) * 8192 + pj] = f2bf(acc0[r]);
        dst[(16 + q * 4 + r) * 8192 + pj] = f2bf(acc1[r]);
      }
    }
  }
}

// ================= T5: flash attention, split-j =================================
__global__ void __launch_bounds__(256, 4) k_attention(
    const u16* __restrict__ Qm, const u16* __restrict__ Km, const u16* __restrict__ Vm,
    const u16* __restrict__ Qx, const u16* __restrict__ Kx, const u16* __restrict__ Vx,
    u16* __restrict__ Opart, float* __restrict__ lpart) {
  const u16 *Qp, *Kp, *Vp;
  int att = blockIdx.z;
  if (att == 0) { Qp = Qm; Kp = Km; Vp = Vx; }   // multi_out
  else          { Qp = Qx; Kp = Kx; Vp = Vm; }   // mono_out
  int sp = blockIdx.y;
  int j0 = sp << 10;                              // 1024 j per split, 16 tiles of 64

  __shared__ u16 Kl[2][64][40];   // [buf][j][ci]
  __shared__ u16 Vl[2][32][72];   // [buf][c][pi-j]

  int t = threadIdx.x, wave = t >> 6, lane = t & 63, ln = lane & 31, h = lane >> 5;
  int iw = blockIdx.x * 128 + wave * 32;

  bf16x8 qf0 = *(const bf16x8*)(Qp + (iw + ln) * 32 + h * 8);
  bf16x8 qf1 = *(const bf16x8*)(Qp + (iw + ln) * 32 + 16 + h * 8);

  int krow = t >> 2, kcol = (t & 3) << 3;
  int vrow = t >> 3, vcol = (t & 7) << 3;
  const u16* Kg = Kp + j0 * 32;
  const u16* Vg = Vp + j0;

  bf16x8 kn = *(const bf16x8*)(Kg + t * 8);
  bf16x8 vn = *(const bf16x8*)(Vg + vrow * 8192 + vcol);
  *(bf16x8*)&Kl[0][krow][kcol] = kn;
  *(bf16x8*)&Vl[0][vrow][vcol] = vn;

  f32x16 O = zero16();
  float lsum = 0.f;

  for (int jt = 0; jt < 16; ++jt) {
    __syncthreads();   // buf[jt&1] writes visible; prior reads of other buf done
    bool have = (jt + 1) < 16;
    if (have) {
      kn = *(const bf16x8*)(Kg + (jt + 1) * 2048 + t * 8);
      vn = *(const bf16x8*)(Vg + vrow * 8192 + (jt + 1) * 64 + vcol);
    }
    int cur = jt & 1;
#pragma unroll
    for (int hh = 0; hh < 2; ++hh) {
      f32x16 s = mfma32(*(const bf16x8*)&Kl[cur][hh * 32 + ln][h * 8], qf0, zero16());
      s = mfma32(*(const bf16x8*)&Kl[cur][hh * 32 + ln][16 + h * 8], qf1, s);
      float e[16];
#pragma unroll
      for (int r = 0; r < 16; ++r) e[r] = __builtin_amdgcn_exp2f(s[r]);
      lsum += sum16(e);
      union PF { bf16x8 v; u32 w[4]; } pf0, pf1;
#pragma unroll
      for (int p = 0; p < 4; ++p) {
        pf0.w[p] = pktr(e[2 * p], e[2 * p + 1]);
        pf1.w[p] = pktr(e[8 + 2 * p], e[8 + 2 * p + 1]);
      }
      bf16x8 vf0 = *(const bf16x8*)&Vl[cur][ln][(2 * hh) * 16 + h * 8];
      bf16x8 vf1 = *(const bf16x8*)&Vl[cur][ln][(2 * hh + 1) * 16 + h * 8];
      O = mfma32(pf0.v, vf0, O);
      O = mfma32(pf1.v, vf1, O);
    }
    if (have) {
      *(bf16x8*)&Kl[1 - cur][krow][kcol] = kn;
      *(bf16x8*)&Vl[1 - cur][vrow][vcol] = vn;
    }
  }
  u16* ob = Opart + (size_t)(att * 8 + sp) * 262144;
  float* lb = lpart + (att * 8 + sp) * 8192;
#pragma unroll
  for (int r = 0; r < 16; ++r) {
    int ig = iw + (r & 3) + 8 * (r >> 2) + 4 * h;
    ob[ig * 32 + ln] = f2bf(O[r]);
  }
  float lo = __shfl(lsum, lane ^ 32, 64);
  float lt = lsum + lo;
  if (lane < 32) lb[iw + lane] = lt;
}

// ---- inline 8-split reduce for one att pixel ----------------------------------
__device__ __forceinline__ void att_reduce(const u16* __restrict__ Opart,
                                           const float* __restrict__ lpart,
                                           int a, int apix, int q, float g,
                                           f32x4& vA, f32x4& vB) {
  f32x4 sA = {0, 0, 0, 0}, sB = {0, 0, 0, 0};
  float l = 0.f;
#pragma unroll
  for (int sp = 0; sp < 8; ++sp) {
    const u16* op = Opart + (size_t)(a * 8 + sp) * 262144 + apix * 32;
    uint2 w0 = *(const uint2*)(op + q * 4);
    uint2 w1 = *(const uint2*)(op + 16 + q * 4);
    sA[0] += bfLO(w0.x); sA[1] += bfHI(w0.x); sA[2] += bfLO(w0.y); sA[3] += bfHI(w0.y);
    sB[0] += bfLO(w1.x); sB[1] += bfHI(w1.x); sB[2] += bfLO(w1.y); sB[3] += bfHI(w1.y);
    l += lpart[(a * 8 + sp) * 8192 + apix];
  }
  float gl = g / l;
#pragma unroll
  for (int r = 0; r < 4; ++r) { vA[r] = sA[r] * gl; vB[r] = sB[r] * gl; }
}

// ================= T6+T7 merged: final epilogues + split reduce =================
__global__ void k_final(const u16* __restrict__ r1T, const u16* __restrict__ cvT,
                        const u16* __restrict__ wConv, const u16* __restrict__ w1x1,
                        const float* mr_b2, const float* xr_b,
                        const u16* __restrict__ Opart, const float* __restrict__ lpart,
                        const float* __restrict__ gamma, float* __restrict__ dout) {
  int bx = blockIdx.x, tid = threadIdx.x;
  int lane = tid & 63, ln = lane & 15, q = lane >> 4;
  float g = gamma[0];
  if (bx < 2048) {
    const u16* w9 = wConv + 5 * 9216;
    int wid = (bx * 256 + tid) >> 6;
    int y = wid >> 5, x0 = (wid & 31) << 4;
    f32x4 acc0 = *(const f32x4*)(mr_b2 + q * 4);
    f32x4 acc1 = *(const f32x4*)(mr_b2 + 16 + q * 4);
    const u16* ib = r1T + (y * 514 + x0 + ln) * 32 + q * 8;
    const u16* wb = w9 + ln * 32 + q * 8;
#pragma unroll
    for (int dy = 0; dy < 3; ++dy)
#pragma unroll
      for (int dx = 0; dx < 3; ++dx) {
        int tap = dy * 3 + dx;
        bf16x8 bf = *(const bf16x8*)(ib + (dy * 514 + dx) * 32);
        acc0 = mfma16(*(const bf16x8*)(wb + tap * 1024), bf, acc0);
        acc1 = mfma16(*(const bf16x8*)(wb + tap * 1024 + 512), bf, acc1);
      }
    int xg = x0 + ln;
    int apix = (y >> 2) * 128 + (xg >> 2);
    f32x4 vA, vB;
    att_reduce(Opart, lpart, 0, apix, q, g, vA, vB);
    float* ob = dout + y * 512 + xg;
#pragma unroll
    for (int r = 0; r < 4; ++r) {
      int co0 = q * 4 + r, co1 = 16 + q * 4 + r;
      ob[co0 * 131072] = fmaxf(acc0[r], 0.f) + vA[r];
      ob[co1 * 131072] = fmaxf(acc1[r], 0.f) + vB[r];
    }
  } else {
    const u16* w = w1x1 + 6 * 1024;
    int wid = ((bx - 2048) * 256 + tid) >> 6;
    int p0 = wid << 4;
    int y = p0 >> 9, x0 = p0 & 511;
    bf16x8 bf = *(const bf16x8*)(cvT + ((y + 1) * 514 + x0 + ln + 1) * 32 + q * 8);
    f32x4 acc0 = *(const f32x4*)(xr_b + q * 4);
    f32x4 acc1 = *(const f32x4*)(xr_b + 16 + q * 4);
    acc0 = mfma16(*(const bf16x8*)(w + ln * 32 + q * 8), bf, acc0);
    acc1 = mfma16(*(const bf16x8*)(w + (16 + ln) * 32 + q * 8), bf, acc1);
    int xg = x0 + ln;
    int apix = (y >> 2) * 128 + (xg >> 2);
    f32x4 vA, vB;
    att_reduce(Opart, lpart, 1, apix, q, g, vA, vB);
    float* ob = dout + 32 * 131072 + p0 + ln;
#pragma unroll
    for (int r = 0; r < 4; ++r) {
      int co0 = q * 4 + r, co1 = 16 + q * 4 + r;
      ob[co0 * 131072] = fmaxf(acc0[r], 0.f) + vA[r];
      ob[co1 * 131072] = fmaxf(acc1[r], 0.f) + vB[r];
    }
  }
}

extern "C" void kernel_launch(void* const* d_in, const int* in_sizes, int n_in,
                              void* d_out, int out_size, void* d_ws, size_t ws_size,
                              hipStream_t stream) {
  const float* mono  = (const float*)d_in[0];
  const float* cv    = (const float*)d_in[1];
  const float* me_b1 = (const float*)d_in[3];
  const float* me_b2 = (const float*)d_in[5];
  const float* xe_b1 = (const float*)d_in[7];
  const float* xe_b2 = (const float*)d_in[9];
  const float* mq_b  = (const float*)d_in[11];
  const float* mk_b  = (const float*)d_in[13];
  const float* mv_b  = (const float*)d_in[15];
  const float* xq_b  = (const float*)d_in[17];
  const float* xk_b  = (const float*)d_in[19];
  const float* xv_b  = (const float*)d_in[21];
  const float* mr_b1 = (const float*)d_in[23];
  const float* mr_b2 = (const float*)d_in[25];
  const float* xr_b  = (const float*)d_in[27];
  const float* gamma = (const float*)d_in[28];
  float* dout = (float*)d_out;

  char* ws = (char*)d_ws;
  u16* wConv = (u16*)(ws + 0);         // 6 * [9][32][32] bf16
  u16* w1x1  = (u16*)(ws + 110592);    // 7 * [32][32] bf16
  u16* monoT = (u16*)(ws + 124928);    // [258][514][32] bf16 (dead after T2)
  u16* Opart = (u16*)(ws + 124928);    // [2][8][8192][32] bf16 — reuses monoT
  u16* cvT   = (u16*)(ws + 8612096);
  u16* m1T   = (u16*)(ws + 17099264);  // [130][258][32]
  u16* x1T   = (u16*)(ws + 19245824);
  u16* r1T   = (u16*)(ws + 21392384);  // [258][514][32]
  u16* Qm    = (u16*)(ws + 30928128);
  u16* Km    = (u16*)(ws + 31452416);
  u16* Vm    = (u16*)(ws + 31976704);  // [32][8192] pi-permuted
  u16* Qx    = (u16*)(ws + 32500992);
  u16* Kx    = (u16*)(ws + 33025280);
  u16* Vx    = (u16*)(ws + 33549568);
  float* lpart = (float*)(ws + 36171008);  // [2][8][8192] fp32

  WPtrs wp;
  wp.p[0] = (const float*)d_in[2];   // me_w1
  wp.p[1] = (const float*)d_in[4];   // me_w2
  wp.p[2] = (const float*)d_in[6];   // xe_w1
  wp.p[3] = (const float*)d_in[8];   // xe_w2
  wp.p[4] = (const float*)d_in[22];  // mr_w1
  wp.p[5] = (const float*)d_in[24];  // mr_w2
  wp.p[6] = (const float*)d_in[10];  // mq_w
  wp.p[7] = (const float*)d_in[12];  // mk_w
  wp.p[8] = (const float*)d_in[14];  // mv_w
  wp.p[9] = (const float*)d_in[16];  // xq_w
  wp.p[10] = (const float*)d_in[18]; // xk_w
  wp.p[11] = (const float*)d_in[20]; // xv_w
  wp.p[12] = (const float*)d_in[26]; // xr_w

  k_pre<<<4234, 256, 0, stream>>>(wp, wConv, w1x1, mono, cv, monoT, cvT, m1T, x1T, r1T);
  k_convs<<<3072, 256, 0, stream>>>(monoT, cvT, wConv, me_b1, xe_b1, mr_b1, m1T, x1T, r1T);
  k_featproj<<<dim3(128, 2), 256, 0, stream>>>(m1T, x1T, wConv, w1x1, me_b2, xe_b2,
                                               mq_b, mk_b, mv_b, xq_b, xk_b, xv_b,
                                               Qm, Km, Vm, Qx, Kx, Vx);
  // DIAGNOSTIC: k_attention x3 (idempotent). dur = 214.6 + 2*t_attn.
  k_attention<<<dim3(64, 8, 2), 256, 0, stream>>>(Qm, Km, Vm, Qx, Kx, Vx, Opart, lpart);
  k_attention<<<dim3(64, 8, 2), 256, 0, stream>>>(Qm, Km, Vm, Qx, Kx, Vx, Opart, lpart);
  k_attention<<<dim3(64, 8, 2), 256, 0, stream>>>(Qm, Km, Vm, Qx, Kx, Vx, Opart, lpart);
  k_final<<<4096, 256, 0, stream>>>(r1T, cvT, wConv, w1x1, mr_b2, xr_b, Opart, lpart, gamma, dout);
}

// Round 12
// 210.658 us; speedup vs baseline: 1.2321x; 1.2321x over previous
//
#include <hip/hip_runtime.h>

// CrossCueFusion on MI355X (gfx950) — round 11 (resubmit after infra timeout).
// r10 measured t_attn = 22.5us (24% of the 95us kernel total; floor ~10-12us ->
// latency/barrier-bound). Changes:
//  (1) attention j-tile 64 -> 128: 8 barriers instead of 16, 4 independent
//      32-row groups per iteration (more ILP). LDS 37.9KB, still 4 blocks/CU.
//  (2) r1-conv (independent of Q/K/V, only feeds k_final) merged into the
//      attention launch as grid [1024,3072) -> runs in attention's shadow.
// k_convs shrinks to the two stride-2 convs. Math bit-identical.

using bf16x8 = __attribute__((ext_vector_type(8))) short;
using f32x4  = __attribute__((ext_vector_type(4))) float;
using f32x16 = __attribute__((ext_vector_type(16))) float;
typedef unsigned short u16;
typedef unsigned int   u32;

__device__ __forceinline__ u16 f2bf(float f) {  // RNE fp32 -> bf16
  u32 u = __builtin_bit_cast(u32, f);
  u = (u + 0x7fffu + ((u >> 16) & 1u)) >> 16;
  return (u16)u;
}
__device__ __forceinline__ float bf2f(u16 v) {
  u32 u = ((u32)v) << 16;
  return __builtin_bit_cast(float, u);
}
__device__ __forceinline__ float bfLO(u32 u) { return __builtin_bit_cast(float, u << 16); }
__device__ __forceinline__ float bfHI(u32 u) { return __builtin_bit_cast(float, u & 0xffff0000u); }
// pack two fp32 -> (bf16 hi|lo) by truncation: one v_perm_b32
__device__ __forceinline__ u32 pktr(float lo, float hi) {
  return __builtin_amdgcn_perm(__builtin_bit_cast(u32, hi),
                               __builtin_bit_cast(u32, lo), 0x07060302u);
}
__device__ __forceinline__ f32x4 mfma16(bf16x8 a, bf16x8 b, f32x4 c) {
  return __builtin_amdgcn_mfma_f32_16x16x32_bf16(a, b, c, 0, 0, 0);
}
__device__ __forceinline__ f32x16 mfma32(bf16x8 a, bf16x8 b, f32x16 c) {
  return __builtin_amdgcn_mfma_f32_32x32x16_bf16(a, b, c, 0, 0, 0);
}
__device__ __forceinline__ f32x16 zero16() {
  f32x16 z = {0,0,0,0,0,0,0,0,0,0,0,0,0,0,0,0};
  return z;
}
__device__ __forceinline__ void store4bf(u16* dst, f32x4 v) {
  u32 lo = (u32)f2bf(v[0]) | ((u32)f2bf(v[1]) << 16);
  u32 hi = (u32)f2bf(v[2]) | ((u32)f2bf(v[3]) << 16);
  *(uint2*)dst = make_uint2(lo, hi);
}
__device__ __forceinline__ float sum16(const float* e) {  // pairwise tree, depth 4
  float s0 = e[0] + e[1], s1 = e[2] + e[3], s2 = e[4] + e[5], s3 = e[6] + e[7];
  float s4 = e[8] + e[9], s5 = e[10] + e[11], s6 = e[12] + e[13], s7 = e[14] + e[15];
  float a = s0 + s1, b = s2 + s3, c = s4 + s5, d = s6 + s7;
  return (a + b) + (c + d);
}

struct WPtrs { const float* p[13]; };

// ================= T1: weight prep + border zero + transpose (fused) ============
// grid: [0,13) prep | [13,138) zero-borders | [138,4234) transpose
__global__ void k_pre(WPtrs wp, u16* __restrict__ wConv, u16* __restrict__ w1x1,
                      const float* __restrict__ mono, const float* __restrict__ cv,
                      u16* __restrict__ monoT, u16* __restrict__ cvT,
                      u16* __restrict__ m1T, u16* __restrict__ x1T, u16* __restrict__ r1T) {
  int bx = blockIdx.x, t = threadIdx.x;
  if (bx < 13) {
    if (bx < 6) {
      const float* s = wp.p[bx];
      u16* d = wConv + bx * 9216;  // [tap][co][ci]
      for (int i = t; i < 9216; i += 256) {
        int tap = i >> 10, co = (i >> 5) & 31, ci = i & 31;
        d[i] = f2bf(s[co * 288 + ci * 9 + tap]);
      }
    } else {
      const float* s = wp.p[bx];
      u16* d = w1x1 + (bx - 6) * 1024;
      for (int i = t; i < 1024; i += 256) d[i] = f2bf(s[i]);
    }
    return;
  }
  if (bx < 138) {
    int zb = bx - 13;
    int buf = zb % 5, blk = zb / 5;
    u16* b; int Hp, Wp;
    switch (buf) {
      case 0: b = monoT; Hp = 258; Wp = 514; break;
      case 1: b = cvT;   Hp = 258; Wp = 514; break;
      case 2: b = m1T;   Hp = 130; Wp = 258; break;
      case 3: b = x1T;   Hp = 130; Wp = 258; break;
      default: b = r1T;  Hp = 258; Wp = 514; break;
    }
    int id = blk * 256 + t;
    int cell = id >> 2, c8 = (id & 3) << 3;
    if (cell >= 2 * (Hp + Wp)) return;
    int r, c;
    if (cell < Wp)              { r = 0;                 c = cell; }
    else if (cell < 2 * Wp)     { r = Hp - 1;            c = cell - Wp; }
    else if (cell < 2 * Wp + Hp){ r = cell - 2 * Wp;     c = 0; }
    else                        { r = cell - 2 * Wp - Hp; c = Wp - 1; }
    bf16x8 z = {0, 0, 0, 0, 0, 0, 0, 0};
    *(bf16x8*)&b[(r * Wp + c) * 32 + c8] = z;
    return;
  }
  // transpose NCHW fp32 -> padded HWC bf16
  int idx = bx - 138;
  int xb = idx & 7, y = (idx >> 3) & 255, z = idx >> 11;
  const float* src = z ? cv : mono;
  u16* dst = z ? cvT : monoT;
  int x0 = xb << 6;
  __shared__ u16 tile[64][40];
  int ci = t >> 3, kx = (t & 7) << 3;
  const float* sp = src + ci * 131072 + y * 512 + x0 + kx;
  float4 a = *(const float4*)sp;
  float4 bb = *(const float4*)(sp + 4);
  tile[kx + 0][ci] = f2bf(a.x); tile[kx + 1][ci] = f2bf(a.y);
  tile[kx + 2][ci] = f2bf(a.z); tile[kx + 3][ci] = f2bf(a.w);
  tile[kx + 4][ci] = f2bf(bb.x); tile[kx + 5][ci] = f2bf(bb.y);
  tile[kx + 6][ci] = f2bf(bb.z); tile[kx + 7][ci] = f2bf(bb.w);
  __syncthreads();
  int x = t >> 2, c8 = (t & 3) << 3;
  bf16x8 v = *(bf16x8*)&tile[x][c8];
  *(bf16x8*)(dst + ((y + 1) * 514 + (x0 + x + 1)) * 32 + c8) = v;
}

// ================= shared 3x3 conv body (16 px x 32 co per wave) ================
__device__ __forceinline__ void conv3x3_body(int bxl, int tid,
    const u16* __restrict__ inT, int Wp, const u16* __restrict__ w9,
    const float* __restrict__ bias, u16* __restrict__ out, int outPitch,
    int outOff, int Ho, int tprShift, int stride) {
  int wid = (bxl * 256 + tid) >> 6;
  int lane = tid & 63, ln = lane & 15, q = lane >> 4;
  int y = wid >> tprShift;
  int x0 = (wid & ((1 << tprShift) - 1)) << 4;
  if (y >= Ho) return;
  f32x4 acc0 = *(const f32x4*)(bias + q * 4);
  f32x4 acc1 = *(const f32x4*)(bias + 16 + q * 4);
  const u16* ib = inT + (stride * y * Wp + stride * (x0 + ln)) * 32 + q * 8;
  const u16* wb = w9 + ln * 32 + q * 8;
#pragma unroll
  for (int dy = 0; dy < 3; ++dy)
#pragma unroll
    for (int dx = 0; dx < 3; ++dx) {
      int tap = dy * 3 + dx;
      bf16x8 bf = *(const bf16x8*)(ib + (dy * Wp + dx) * 32);
      acc0 = mfma16(*(const bf16x8*)(wb + tap * 1024), bf, acc0);
      acc1 = mfma16(*(const bf16x8*)(wb + tap * 1024 + 512), bf, acc1);
    }
#pragma unroll
  for (int r = 0; r < 4; ++r) { acc0[r] = fmaxf(acc0[r], 0.f); acc1[r] = fmaxf(acc1[r], 0.f); }
  u16* ob = out + (outOff + y * outPitch + x0 + ln) * 32;
  store4bf(ob + q * 4, acc0);
  store4bf(ob + 16 + q * 4, acc1);
}

// ================= T2: the two stride-2 feature convs ===========================
// [0,512) mono stride-2 | [512,1024) cv stride-2   (r1 conv moved to k_attnconv)
__global__ void k_convs(const u16* __restrict__ monoT, const u16* __restrict__ cvT,
                        const u16* __restrict__ wConv,
                        const float* me_b1, const float* xe_b1,
                        u16* __restrict__ m1T, u16* __restrict__ x1T) {
  int bx = blockIdx.x;
  if (bx < 512)
    conv3x3_body(bx, threadIdx.x, monoT, 514, wConv + 0 * 9216, me_b1, m1T, 258, 259, 128, 4, 2);
  else
    conv3x3_body(bx - 512, threadIdx.x, cvT, 514, wConv + 2 * 9216, xe_b1, x1T, 258, 259, 128, 4, 2);
}

// ================= T3+T4 merged: feature conv + q/k/v projections ===============
// grid (128, 2): y=0 mono branch (which 0..2), y=1 multi branch (which 3..5).
__global__ void k_featproj(const u16* __restrict__ m1T, const u16* __restrict__ x1T,
                           const u16* __restrict__ wConv, const u16* __restrict__ w1x1,
                           const float* me_b2, const float* xe_b2,
                           const float* mq_b, const float* mk_b, const float* mv_b,
                           const float* xq_b, const float* xk_b, const float* xv_b,
                           u16* Qm, u16* Km, u16* Vm, u16* Qx, u16* Kx, u16* Vx) {
  int bx = blockIdx.x, br = blockIdx.y;
  const u16* inT = br ? x1T : m1T;
  const u16* w9 = wConv + (br ? 3 : 1) * 9216;
  const float* bias2 = br ? xe_b2 : me_b2;
  __shared__ u16 fs[64][40];
  int tid = threadIdx.x, wave = tid >> 6, lane = tid & 63, ln = lane & 15, q = lane >> 4;
  int fy = bx >> 1, x0 = (bx & 1) * 64 + wave * 16;  // feat image [64][128]
  {
    f32x4 acc0 = *(const f32x4*)(bias2 + q * 4);
    f32x4 acc1 = *(const f32x4*)(bias2 + 16 + q * 4);
    const u16* ib = inT + (2 * fy * 258 + 2 * (x0 + ln)) * 32 + q * 8;
    const u16* wb = w9 + ln * 32 + q * 8;
#pragma unroll
    for (int dy = 0; dy < 3; ++dy)
#pragma unroll
      for (int dx = 0; dx < 3; ++dx) {
        int tap = dy * 3 + dx;
        bf16x8 bf = *(const bf16x8*)(ib + (dy * 258 + dx) * 32);
        acc0 = mfma16(*(const bf16x8*)(wb + tap * 1024), bf, acc0);
        acc1 = mfma16(*(const bf16x8*)(wb + tap * 1024 + 512), bf, acc1);
      }
#pragma unroll
    for (int r = 0; r < 4; ++r) { acc0[r] = fmaxf(acc0[r], 0.f); acc1[r] = fmaxf(acc1[r], 0.f); }
    int row = wave * 16 + ln;
    store4bf(&fs[row][q * 4], acc0);
    store4bf(&fs[row][16 + q * 4], acc1);
  }
  __syncthreads();
  int p = fy * 128 + x0 + ln;                       // global pixel [0,8192)
  bf16x8 bf = *(const bf16x8*)&fs[wave * 16 + ln][q * 8];
#pragma unroll
  for (int wh = 0; wh < 3; ++wh) {
    int which = br * 3 + wh;
    const float* bias; u16* dst; float scale = 1.f; int cmode = 0;
    switch (which) {
      case 0: bias = mq_b; dst = Qm; scale = 1.4426950408889634f; break;
      case 1: bias = mk_b; dst = Km; break;
      case 2: bias = mv_b; dst = Vm; cmode = 1; break;
      case 3: bias = xq_b; dst = Qx; scale = 1.4426950408889634f; break;
      case 4: bias = xk_b; dst = Kx; break;
      default: bias = xv_b; dst = Vx; cmode = 1; break;
    }
    const u16* w = w1x1 + which * 1024;
    bf16x8 a0 = *(const bf16x8*)(w + ln * 32 + q * 8);
    bf16x8 a1 = *(const bf16x8*)(w + (16 + ln) * 32 + q * 8);
    f32x4 acc0 = *(const f32x4*)(bias + q * 4);
    f32x4 acc1 = *(const f32x4*)(bias + 16 + q * 4);
    acc0 = mfma16(a0, bf, acc0);
    acc1 = mfma16(a1, bf, acc1);
#pragma unroll
    for (int r = 0; r < 4; ++r) { acc0[r] *= scale; acc1[r] *= scale; }
    if (!cmode) {  // i-major [8192][32]
      store4bf(dst + p * 32 + q * 4, acc0);
      store4bf(dst + p * 32 + 16 + q * 4, acc1);
    } else {       // c-major, pi-permuted within each 64-column block
      int jl = p & 63, jb = p & ~63;
      int pj = jb + (jl >> 5) * 32 + ((jl >> 4) & 1) * 16 + ((jl >> 2) & 1) * 8
             + ((jl >> 3) & 1) * 4 + (jl & 3);
#pragma unroll
      for (int r = 0; r < 4; ++r) {
        dst[(q * 4 + r) * 8192 + pj] = f2bf(acc0[r]);
        dst[(16 + q * 4 + r) * 8192 + pj] = f2bf(acc1[r]);
      }
    }
  }
}

// ================= T5: flash attention (j-tile 128) + r1 conv (merged) ==========
// grid 3072: [0,1024) attention (ib 64, sp 8, att 2) | [1024,3072) mono residual
// stride-1 conv (independent of Q/K/V; backfills CUs as attention retires).
// Attention: 8 j-iterations of 128 (4 groups of 32 rows), double-buffered LDS.
__global__ void __launch_bounds__(256, 4) k_attnconv(
    const u16* __restrict__ Qm, const u16* __restrict__ Km, const u16* __restrict__ Vm,
    const u16* __restrict__ Qx, const u16* __restrict__ Kx, const u16* __restrict__ Vx,
    const u16* __restrict__ monoT, const u16* __restrict__ wConv, const float* mr_b1,
    u16* __restrict__ r1T, u16* __restrict__ Opart, float* __restrict__ lpart) {
  int vb = blockIdx.x;
  if (vb >= 1024) {  // r1 conv: 3x3 stride-1 on monoT -> r1T (padded)
    conv3x3_body(vb - 1024, threadIdx.x, monoT, 514, wConv + 4 * 9216, mr_b1,
                 r1T, 514, 515, 256, 5, 1);
    return;
  }
  int ib = vb & 63, sp = (vb >> 6) & 7, att = vb >> 9;
  const u16 *Qp, *Kp, *Vp;
  if (att == 0) { Qp = Qm; Kp = Km; Vp = Vx; }   // multi_out
  else          { Qp = Qx; Kp = Kx; Vp = Vm; }   // mono_out

  __shared__ u16 Kl[2][128][40];  // [buf][j][ci]   20480 B
  __shared__ u16 Vl[2][32][136];  // [buf][c][pi-j] 17408 B

  int t = threadIdx.x, wave = t >> 6, lane = t & 63, ln = lane & 31, h = lane >> 5;
  int iw = ib * 128 + wave * 32;

  bf16x8 qf0 = *(const bf16x8*)(Qp + (iw + ln) * 32 + h * 8);
  bf16x8 qf1 = *(const bf16x8*)(Qp + (iw + ln) * 32 + 16 + h * 8);

  // staging: K tile 128x32 u16 = 256 thr x 16 u16; V tile 32x128 = 256 thr x 16
  int krow = t >> 1, kcol = (t & 1) << 4;
  int vrow = t >> 3, vcol = (t & 7) << 4;
  const u16* Kg = Kp + sp * 32768;   // slice rows [sp*1024, +1024), 32 u16/row
  const u16* Vg = Vp + sp * 1024;    // slice cols [sp*1024, +1024) per c-row

  bf16x8 kn0 = *(const bf16x8*)(Kg + t * 16);
  bf16x8 kn1 = *(const bf16x8*)(Kg + t * 16 + 8);
  bf16x8 vn0 = *(const bf16x8*)(Vg + vrow * 8192 + vcol);
  bf16x8 vn1 = *(const bf16x8*)(Vg + vrow * 8192 + vcol + 8);
  *(bf16x8*)&Kl[0][krow][kcol] = kn0;
  *(bf16x8*)&Kl[0][krow][kcol + 8] = kn1;
  *(bf16x8*)&Vl[0][vrow][vcol] = vn0;
  *(bf16x8*)&Vl[0][vrow][vcol + 8] = vn1;

  f32x16 O = zero16();
  float lsum = 0.f;

  for (int jt = 0; jt < 8; ++jt) {
    __syncthreads();   // buf[jt&1] writes visible; prior reads of other buf done
    bool have = (jt + 1) < 8;
    if (have) {
      kn0 = *(const bf16x8*)(Kg + (jt + 1) * 4096 + t * 16);
      kn1 = *(const bf16x8*)(Kg + (jt + 1) * 4096 + t * 16 + 8);
      vn0 = *(const bf16x8*)(Vg + vrow * 8192 + (jt + 1) * 128 + vcol);
      vn1 = *(const bf16x8*)(Vg + vrow * 8192 + (jt + 1) * 128 + vcol + 8);
    }
    int cur = jt & 1;
#pragma unroll
    for (int g = 0; g < 4; ++g) {
      // 32 j-rows of S^T (rows j in regs, cols i = ln)
      f32x16 s = mfma32(*(const bf16x8*)&Kl[cur][g * 32 + ln][h * 8], qf0, zero16());
      s = mfma32(*(const bf16x8*)&Kl[cur][g * 32 + ln][16 + h * 8], qf1, s);
      float e[16];
#pragma unroll
      for (int r = 0; r < 16; ++r) e[r] = __builtin_amdgcn_exp2f(s[r]);
      lsum += sum16(e);
      union PF { bf16x8 v; u32 w[4]; } pf0, pf1;
#pragma unroll
      for (int p = 0; p < 4; ++p) {
        pf0.w[p] = pktr(e[2 * p], e[2 * p + 1]);
        pf1.w[p] = pktr(e[8 + 2 * p], e[8 + 2 * p + 1]);
      }
      bf16x8 vf0 = *(const bf16x8*)&Vl[cur][ln][g * 32 + h * 8];
      bf16x8 vf1 = *(const bf16x8*)&Vl[cur][ln][g * 32 + 16 + h * 8];
      O = mfma32(pf0.v, vf0, O);
      O = mfma32(pf1.v, vf1, O);
    }
    if (have) {
      *(bf16x8*)&Kl[1 - cur][krow][kcol] = kn0;
      *(bf16x8*)&Kl[1 - cur][krow][kcol + 8] = kn1;
      *(bf16x8*)&Vl[1 - cur][vrow][vcol] = vn0;
      *(bf16x8*)&Vl[1 - cur][vrow][vcol + 8] = vn1;
    }
  }
  // write partials: O rows i = (r&3)+8*(r>>2)+4*h, cols c = ln
  u16* ob = Opart + (size_t)(att * 8 + sp) * 262144;
  float* lb = lpart + (att * 8 + sp) * 8192;
#pragma unroll
  for (int r = 0; r < 16; ++r) {
    int ig = iw + (r & 3) + 8 * (r >> 2) + 4 * h;
    ob[ig * 32 + ln] = f2bf(O[r]);
  }
  // l[i] = lsum(lane i) + lsum(lane i+32)  (complementary j-slices mod 8)
  float lo = __shfl(lsum, lane ^ 32, 64);
  float lt = lsum + lo;
  if (lane < 32) lb[iw + lane] = lt;
}

// ---- inline 8-split reduce for one att pixel ----------------------------------
__device__ __forceinline__ void att_reduce(const u16* __restrict__ Opart,
                                           const float* __restrict__ lpart,
                                           int a, int apix, int q, float g,
                                           f32x4& vA, f32x4& vB) {
  f32x4 sA = {0, 0, 0, 0}, sB = {0, 0, 0, 0};
  float l = 0.f;
#pragma unroll
  for (int sp = 0; sp < 8; ++sp) {
    const u16* op = Opart + (size_t)(a * 8 + sp) * 262144 + apix * 32;
    uint2 w0 = *(const uint2*)(op + q * 4);
    uint2 w1 = *(const uint2*)(op + 16 + q * 4);
    sA[0] += bfLO(w0.x); sA[1] += bfHI(w0.x); sA[2] += bfLO(w0.y); sA[3] += bfHI(w0.y);
    sB[0] += bfLO(w1.x); sB[1] += bfHI(w1.x); sB[2] += bfLO(w1.y); sB[3] += bfHI(w1.y);
    l += lpart[(a * 8 + sp) * 8192 + apix];
  }
  float gl = g / l;
#pragma unroll
  for (int r = 0; r < 4; ++r) { vA[r] = sA[r] * gl; vB[r] = sB[r] * gl; }
}

// ================= T6+T7 merged: final epilogues + split reduce =================
__global__ void k_final(const u16* __restrict__ r1T, const u16* __restrict__ cvT,
                        const u16* __restrict__ wConv, const u16* __restrict__ w1x1,
                        const float* mr_b2, const float* xr_b,
                        const u16* __restrict__ Opart, const float* __restrict__ lpart,
                        const float* __restrict__ gamma, float* __restrict__ dout) {
  int bx = blockIdx.x, tid = threadIdx.x;
  int lane = tid & 63, ln = lane & 15, q = lane >> 4;
  float g = gamma[0];
  if (bx < 2048) {
    const u16* w9 = wConv + 5 * 9216;
    int wid = (bx * 256 + tid) >> 6;
    int y = wid >> 5, x0 = (wid & 31) << 4;
    f32x4 acc0 = *(const f32x4*)(mr_b2 + q * 4);
    f32x4 acc1 = *(const f32x4*)(mr_b2 + 16 + q * 4);
    const u16* ib = r1T + (y * 514 + x0 + ln) * 32 + q * 8;
    const u16* wb = w9 + ln * 32 + q * 8;
#pragma unroll
    for (int dy = 0; dy < 3; ++dy)
#pragma unroll
      for (int dx = 0; dx < 3; ++dx) {
        int tap = dy * 3 + dx;
        bf16x8 bf = *(const bf16x8*)(ib + (dy * 514 + dx) * 32);
        acc0 = mfma16(*(const bf16x8*)(wb + tap * 1024), bf, acc0);
        acc1 = mfma16(*(const bf16x8*)(wb + tap * 1024 + 512), bf, acc1);
      }
    int xg = x0 + ln;
    int apix = (y >> 2) * 128 + (xg >> 2);
    f32x4 vA, vB;
    att_reduce(Opart, lpart, 0, apix, q, g, vA, vB);
    float* ob = dout + y * 512 + xg;
#pragma unroll
    for (int r = 0; r < 4; ++r) {
      int co0 = q * 4 + r, co1 = 16 + q * 4 + r;
      ob[co0 * 131072] = fmaxf(acc0[r], 0.f) + vA[r];
      ob[co1 * 131072] = fmaxf(acc1[r], 0.f) + vB[r];
    }
  } else {
    const u16* w = w1x1 + 6 * 1024;
    int wid = ((bx - 2048) * 256 + tid) >> 6;
    int p0 = wid << 4;
    int y = p0 >> 9, x0 = p0 & 511;
    bf16x8 bf = *(const bf16x8*)(cvT + ((y + 1) * 514 + x0 + ln + 1) * 32 + q * 8);
    f32x4 acc0 = *(const f32x4*)(xr_b + q * 4);
    f32x4 acc1 = *(const f32x4*)(xr_b + 16 + q * 4);
    acc0 = mfma16(*(const bf16x8*)(w + ln * 32 + q * 8), bf, acc0);
    acc1 = mfma16(*(const bf16x8*)(w + (16 + ln) * 32 + q * 8), bf, acc1);
    int xg = x0 + ln;
    int apix = (y >> 2) * 128 + (xg >> 2);
    f32x4 vA, vB;
    att_reduce(Opart, lpart, 1, apix, q, g, vA, vB);
    float* ob = dout + 32 * 131072 + p0 + ln;
#pragma unroll
    for (int r = 0; r < 4; ++r) {
      int co0 = q * 4 + r, co1 = 16 + q * 4 + r;
      ob[co0 * 131072] = fmaxf(acc0[r], 0.f) + vA[r];
      ob[co1 * 131072] = fmaxf(acc1[r], 0.f) + vB[r];
    }
  }
}

extern "C" void kernel_launch(void* const* d_in, const int* in_sizes, int n_in,
                              void* d_out, int out_size, void* d_ws, size_t ws_size,
                              hipStream_t stream) {
  const float* mono  = (const float*)d_in[0];
  const float* cv    = (const float*)d_in[1];
  const float* me_b1 = (const float*)d_in[3];
  const float* me_b2 = (const float*)d_in[5];
  const float* xe_b1 = (const float*)d_in[7];
  const float* xe_b2 = (const float*)d_in[9];
  const float* mq_b  = (const float*)d_in[11];
  const float* mk_b  = (const float*)d_in[13];
  const float* mv_b  = (const float*)d_in[15];
  const float* xq_b  = (const float*)d_in[17];
  const float* xk_b  = (const float*)d_in[19];
  const float* xv_b  = (const float*)d_in[21];
  const float* mr_b1 = (const float*)d_in[23];
  const float* mr_b2 = (const float*)d_in[25];
  const float* xr_b  = (const float*)d_in[27];
  const float* gamma = (const float*)d_in[28];
  float* dout = (float*)d_out;

  char* ws = (char*)d_ws;
  u16* wConv = (u16*)(ws + 0);         // 6 * [9][32][32] bf16
  u16* w1x1  = (u16*)(ws + 110592);    // 7 * [32][32] bf16
  u16* monoT = (u16*)(ws + 124928);    // [258][514][32] bf16
  u16* cvT   = (u16*)(ws + 8612096);
  u16* m1T   = (u16*)(ws + 17099264);  // [130][258][32]
  u16* x1T   = (u16*)(ws + 19245824);
  u16* r1T   = (u16*)(ws + 21392384);  // [258][514][32]
  u16* Qm    = (u16*)(ws + 30928128);
  u16* Km    = (u16*)(ws + 31452416);
  u16* Vm    = (u16*)(ws + 31976704);  // [32][8192] pi-permuted
  u16* Qx    = (u16*)(ws + 32500992);
  u16* Kx    = (u16*)(ws + 33025280);
  u16* Vx    = (u16*)(ws + 33549568);
  float* lpart = (float*)(ws + 36171008);  // [2][8][8192] fp32
  // Opart gets dedicated space (no monoT alias: conv blocks in k_attnconv read
  // monoT concurrently with attention blocks writing Opart).
  u16* Opart = (u16*)(ws + 37219840);  // [2][8][8192][32] bf16 = 8.4 MB

  WPtrs wp;
  wp.p[0] = (const float*)d_in[2];   // me_w1
  wp.p[1] = (const float*)d_in[4];   // me_w2
  wp.p[2] = (const float*)d_in[6];   // xe_w1
  wp.p[3] = (const float*)d_in[8];   // xe_w2
  wp.p[4] = (const float*)d_in[22];  // mr_w1
  wp.p[5] = (const float*)d_in[24];  // mr_w2
  wp.p[6] = (const float*)d_in[10];  // mq_w
  wp.p[7] = (const float*)d_in[12];  // mk_w
  wp.p[8] = (const float*)d_in[14];  // mv_w
  wp.p[9] = (const float*)d_in[16];  // xq_w
  wp.p[10] = (const float*)d_in[18]; // xk_w
  wp.p[11] = (const float*)d_in[20]; // xv_w
  wp.p[12] = (const float*)d_in[26]; // xr_w

  k_pre<<<4234, 256, 0, stream>>>(wp, wConv, w1x1, mono, cv, monoT, cvT, m1T, x1T, r1T);
  k_convs<<<1024, 256, 0, stream>>>(monoT, cvT, wConv, me_b1, xe_b1, m1T, x1T);
  k_featproj<<<dim3(128, 2), 256, 0, stream>>>(m1T, x1T, wConv, w1x1, me_b2, xe_b2,
                                               mq_b, mk_b, mv_b, xq_b, xk_b, xv_b,
                                               Qm, Km, Vm, Qx, Kx, Vx);
  k_attnconv<<<3072, 256, 0, stream>>>(Qm, Km, Vm, Qx, Kx, Vx,
                                       monoT, wConv, mr_b1, r1T, Opart, lpart);
  k_final<<<4096, 256, 0, stream>>>(r1T, cvT, wConv, w1x1, mr_b2, xr_b, Opart, lpart, gamma, dout);
}